// Round 20
// baseline (370.385 us; speedup 1.0000x reference)
//
#include <hip/hip_runtime.h>
#include <cmath>

typedef unsigned short ushort_t;
typedef __attribute__((ext_vector_type(8))) short short8;
typedef __attribute__((ext_vector_type(4))) float f32x4;
typedef __attribute__((ext_vector_type(4))) short short4v;

static constexpr int NSEQ = 2048, DM = 1024, DI = 512;
static constexpr size_t NN = (size_t)NSEQ * NSEQ;

__device__ __forceinline__ ushort_t f2b(float v) {
    unsigned u = __float_as_uint(v);
    return (ushort_t)((u + 0x7fffu + ((u >> 16) & 1u)) >> 16);  // RTNE
}
__device__ __forceinline__ float b2f(ushort_t b) { return __uint_as_float(((unsigned)b) << 16); }
__device__ __forceinline__ float sigm(float x) { return 1.f / (1.f + expf(-x)); }
__device__ __forceinline__ float silu(float x) { return x / (1.f + expf(-x)); }

#define MFMA16(a, b, c) __builtin_amdgcn_mfma_f32_16x16x32_bf16(a, b, c, 0, 0, 0)

// counted-vmcnt waits (T4): never drain to 0 mid-loop
__device__ __forceinline__ void wait_vm8() { asm volatile("s_waitcnt vmcnt(8)" ::: "memory"); }
__device__ __forceinline__ void wait_vm3() { asm volatile("s_waitcnt vmcnt(3)" ::: "memory"); }
__device__ __forceinline__ void wait_vm4() { asm volatile("s_waitcnt vmcnt(4)" ::: "memory"); }
__device__ __forceinline__ void wait_vm0() { asm volatile("s_waitcnt vmcnt(0)" ::: "memory"); }

// ---- async global->LDS staging, source pre-swizzled (rule #21) ------------------
__device__ __forceinline__ void gll16(const ushort_t* g, ushort_t* l) {
    __builtin_amdgcn_global_load_lds((const __attribute__((address_space(1))) void*)g,
                                     (__attribute__((address_space(3))) void*)l, 16, 0, 0);
}
__device__ __forceinline__ void stage16(const ushort_t* g, int ldg, ushort_t* lds, int q) {
    const int l = threadIdx.x & 63;
    const int row = l >> 2;
    const int ch = (l & 3) ^ ((l >> 3) & 3);
    gll16(g + (size_t)(q * 16 + row) * ldg + ch * 8, lds + q * 512);
}
__device__ __forceinline__ short8 lfrag(const ushort_t* t, int row0, int lane) {
    const int row = row0 + (lane & 15);
    const int ch = (lane >> 4) ^ ((row >> 1) & 3);
    return *(const short8*)(t + row * 32 + (ch << 3));
}
// descending-length triangular pair decode: p in [0,136) -> (lo, lo+d), d=15..0
__device__ __forceinline__ void pair_decode(int p, int& lo, int& d) {
    d = 15;
    int cnt = 1;
    while (p >= cnt) { p -= cnt; --d; cnt = 16 - d; }
    lo = p;
}

// ---- one-shot f32 -> bf16 hi(/lo) -----------------------------------------------
__global__ __launch_bounds__(256) void k_cvt(const float4* __restrict__ src,
                                             ushort_t* __restrict__ hi,
                                             ushort_t* __restrict__ lo, int n4, int has_lo) {
    for (int i = blockIdx.x * 256 + threadIdx.x; i < n4; i += gridDim.x * 256) {
        float4 f = src[i];
        float a[4] = {f.x, f.y, f.z, f.w};
        short4v hv, lv;
#pragma unroll
        for (int j = 0; j < 4; ++j) {
            ushort_t h = f2b(a[j]);
            hv[j] = (short)h;
            lv[j] = (short)f2b(a[j] - b2f(h));
        }
        *(short4v*)(hi + (size_t)i * 4) = hv;
        if (has_lo) *(short4v*)(lo + (size_t)i * 4) = lv;
    }
}

// ---- proj: qkv = x @ Wqkv^T (single bf16), 3-buf depth-2, unroll-3 static bufs --
__global__ __launch_bounds__(256) void k_proj(const ushort_t* __restrict__ xh,
                                              const ushort_t* __restrict__ wh,
                                              ushort_t* __restrict__ qh,
                                              ushort_t* __restrict__ vcT) {
    __shared__ __align__(16) ushort_t lds[3][8192];    // [A|B] 16KB/buf
    const int flat = blockIdx.x + 24 * blockIdx.y;
    const int p = (flat & 7) * 96 + (flat >> 3);
    const int bx = p % 24, by = p / 24;
    const int m0 = by * 128, n0 = bx * 128;
    const int l = threadIdx.x & 63, w = threadIdx.x >> 6;
    const int mb = (w >> 1) * 64, nb = (w & 1) * 64;
    const ushort_t* matA = xh + (size_t)m0 * DM;
    const ushort_t* matB = wh + (size_t)n0 * DM;
    const bool stager = (w == 0 || w == 1);
    auto STAGE = [&](int t, ushort_t* buf) {
        if (t >= 32 || !stager) return;
        const ushort_t* src = (w == 0) ? matA + t * 32 : matB + t * 32;
        ushort_t* dst = buf + ((w == 0) ? 0 : 4096);
        for (int q = 0; q < 8; ++q) stage16(src, DM, dst, q);
    };
    f32x4 acc[4][4] = {};
    auto BODY = [&](int t, const ushort_t* cur, ushort_t* stg) {
        if (t + 1 < 32 && stager) wait_vm8(); else wait_vm0();
        __builtin_amdgcn_s_barrier();
        STAGE(t + 2, stg);
        short8 fah[4], fbh[4];
#pragma unroll
        for (int i = 0; i < 4; ++i) fah[i] = lfrag(cur, mb + i * 16, l);
#pragma unroll
        for (int j = 0; j < 4; ++j) fbh[j] = lfrag(cur + 4096, nb + j * 16, l);
#pragma unroll
        for (int i = 0; i < 4; ++i)
#pragma unroll
            for (int j = 0; j < 4; ++j) acc[i][j] = MFMA16(fah[i], fbh[j], acc[i][j]);
    };
    STAGE(0, lds[0]);
    STAGE(1, lds[1]);
    for (int t = 0; t < 32; t += 3) {
        BODY(t, lds[0], lds[2]);
        if (t + 1 < 32) BODY(t + 1, lds[1], lds[0]);
        if (t + 2 < 32) BODY(t + 2, lds[2], lds[1]);
    }
#pragma unroll
    for (int i = 0; i < 4; ++i)
#pragma unroll
        for (int j = 0; j < 4; ++j)
#pragma unroll
            for (int r = 0; r < 4; ++r) {
                int m = m0 + mb + i * 16 + (l >> 4) * 4 + r;
                int n = n0 + nb + j * 16 + (l & 15);
                float v = acc[i][j][r];
                int tt = n >> 9, head = (n >> 6) & 7, dd = n & 63;
                int b = m >> 11, np = m & 2047;
                if (tt == 0 || tt == 3) v *= 0.125f;
                ushort_t h = f2b(v);
                size_t off = (size_t)(tt * 16 + b * 8 + head) * 131072 + (size_t)np * 64 + dd;
                qh[off] = h;
                if (tt == 5) vcT[(size_t)(b * 8 + head) * 131072 + (size_t)dd * 2048 + np] = h;
            }
}

// ---- tl: mode0 t1 = qc.vu^T (hi), mode1 look = sigm(qu.ku^T) (hi); 32KB LDS -----
__global__ __launch_bounds__(256) void k_tl(const ushort_t* __restrict__ qkvh,
                                            ushort_t* __restrict__ Ph,
                                            ushort_t* __restrict__ t1dh,
                                            ushort_t* __restrict__ lkdh, int g0) {
    const int mode = blockIdx.x & 1, z = blockIdx.x >> 1, hh = g0 + z;
    int lo_t, d;
    pair_decode(blockIdx.y, lo_t, d);
    const int by = mode ? lo_t : lo_t + d;      // mode0: by=i (>=bx); mode1: by=k (<=bx)
    const int bx = mode ? lo_t + d : lo_t;
    __shared__ __align__(16) ushort_t lds[2][8192];    // [A|B] 16KB/buf
    const int l = threadIdx.x & 63, w = threadIdx.x >> 6;
    const int mb = (w >> 1) * 64, nb = (w & 1) * 64;
    const int ta = mode ? 0 : 3, tb = mode ? 1 : 2;
    const ushort_t* matA = qkvh + (size_t)(ta * 16 + hh) * 131072 + (size_t)(by * 128) * 64;
    const ushort_t* matB = qkvh + (size_t)(tb * 16 + hh) * 131072 + (size_t)(bx * 128) * 64;
    auto STAGE = [&](int t, ushort_t* buf) {
        if (w == 0) for (int q = 0; q < 8; ++q) stage16(matA + t * 32, 64, buf, q);
        else if (w == 1) for (int q = 0; q < 8; ++q) stage16(matB + t * 32, 64, buf + 4096, q);
    };
    STAGE(0, lds[0]);
    __syncthreads();
    f32x4 acc[4][4] = {};
    for (int t = 0; t < 2; ++t) {
        if (t == 0) STAGE(1, lds[1]);
        const ushort_t* buf = lds[t & 1];
        short8 fah[4], fbh[4];
#pragma unroll
        for (int i = 0; i < 4; ++i) fah[i] = lfrag(buf, mb + i * 16, l);
#pragma unroll
        for (int j = 0; j < 4; ++j) fbh[j] = lfrag(buf + 4096, nb + j * 16, l);
#pragma unroll
        for (int i = 0; i < 4; ++i)
#pragma unroll
            for (int j = 0; j < 4; ++j) acc[i][j] = MFMA16(fah[i], fbh[j], acc[i][j]);
        __syncthreads();
    }
    const bool isdiag = (bx == by);
    ushort_t* ph = Ph + (size_t)z * NN;
    if (mode == 0) {
        ushort_t* dh = t1dh + ((size_t)z * 16 + by) * 16384;
#pragma unroll
        for (int i = 0; i < 4; ++i)
#pragma unroll
            for (int j = 0; j < 4; ++j)
#pragma unroll
                for (int r = 0; r < 4; ++r) {
                    int gi = by * 128 + mb + i * 16 + (l >> 4) * 4 + r;
                    int gj = bx * 128 + nb + j * 16 + (l & 15);
                    ushort_t h = f2b(acc[i][j][r]);
                    if (gj <= gi) ph[(size_t)gi * 2048 + gj] = h;
                    if (isdiag) dh[(gi & 127) * 128 + (gj & 127)] = (gj <= gi) ? h : 0;
                }
    } else {
        ushort_t* dh = lkdh + ((size_t)z * 16 + by) * 16384;
#pragma unroll
        for (int i = 0; i < 4; ++i)
#pragma unroll
            for (int j = 0; j < 4; ++j)
#pragma unroll
                for (int r = 0; r < 4; ++r) {
                    int gk = by * 128 + mb + i * 16 + (l >> 4) * 4 + r;
                    int gj = bx * 128 + nb + j * 16 + (l & 15);
                    ushort_t h = f2b(sigm(acc[i][j][r]));
                    if (gj > gk) ph[(size_t)gk * 2048 + gj] = h;
                    if (isdiag) dh[(gk & 127) * 128 + (gj & 127)] = (gj > gk) ? h : 0;
                }
    }
}

// ---- scores: Su mm16 + Sc mm16, 3x16KB buffers, unroll-3 static bufs ------------
__global__ __launch_bounds__(256) void k_scores(const ushort_t* __restrict__ Ph,
                                                const ushort_t* __restrict__ t1dh,
                                                const ushort_t* __restrict__ lkdh,
                                                const ushort_t* __restrict__ qkvh,
                                                float* __restrict__ sc, int g0) {
    const int z = blockIdx.x, hh = g0 + z;
    int bxk, d;
    pair_decode(blockIdx.y, bxk, d);
    const int byi = bxk + d;
    __shared__ __align__(16) ushort_t lds[3][8192];   // [A|B] 16KB/buf, 48KB total
    const int l = threadIdx.x & 63, w = threadIdx.x >> 6;
    const int mb = (w >> 1) * 64, nb = (w & 1) * 64;
    const int nsu = (d + 1) * 4, nt = nsu + 2;
    const ushort_t* pAh = Ph + (size_t)z * NN + (size_t)(byi * 128) * 2048;
    const ushort_t* pBh = Ph + (size_t)z * NN + (size_t)(bxk * 128) * 2048;
    const ushort_t* dAh = t1dh + ((size_t)z * 16 + byi) * 16384;
    const ushort_t* dBh = lkdh + ((size_t)z * 16 + bxk) * 16384;
    const ushort_t* qch = qkvh + (size_t)(3 * 16 + hh) * 131072 + (size_t)(byi * 128) * 64;
    const ushort_t* kch = qkvh + (size_t)(4 * 16 + hh) * 131072 + (size_t)(bxk * 128) * 64;
    const bool stager = (w == 0 || w == 2);
    auto STAGE = [&](int t, ushort_t* buf) {
        if (t >= nt || !stager) return;
        const ushort_t* src;
        int ld;
        if (t < nsu) {
            const int tb = t >> 2, kloc = (t & 3) * 32;
            if (w == 0) {
                if (tb == d) { src = dAh + kloc; ld = 128; }
                else { src = pAh + (bxk + tb) * 128 + kloc; ld = 2048; }
            } else {
                if (tb == 0) { src = dBh + kloc; ld = 128; }
                else { src = pBh + (bxk + tb) * 128 + kloc; ld = 2048; }
            }
        } else {
            const int k0 = (t - nsu) * 32;
            src = (w == 0) ? qch + k0 : kch + k0;
            ld = 64;
        }
        ushort_t* dst = buf + ((w == 0) ? 0 : 4096);
        for (int q = 0; q < 8; ++q) stage16(src, ld, dst, q);
    };
    f32x4 acc[4][4] = {};
    auto BODY = [&](int t, const ushort_t* cur, ushort_t* stg) {
        if (t + 1 < nt && stager) wait_vm8(); else wait_vm0();
        __builtin_amdgcn_s_barrier();   // buf t ready; mm(t-1) reads done
        STAGE(t + 2, stg);
        if (t == nsu) {
#pragma unroll
            for (int i = 0; i < 4; ++i)
#pragma unroll
                for (int j = 0; j < 4; ++j)
#pragma unroll
                    for (int r = 0; r < 4; ++r) acc[i][j][r] = -silu(acc[i][j][r]);
        }
        short8 fah[4], fbh[4];
#pragma unroll
        for (int i = 0; i < 4; ++i) fah[i] = lfrag(cur, mb + i * 16, l);
#pragma unroll
        for (int j = 0; j < 4; ++j) fbh[j] = lfrag(cur + 4096, nb + j * 16, l);
#pragma unroll
        for (int i = 0; i < 4; ++i)
#pragma unroll
            for (int j = 0; j < 4; ++j) acc[i][j] = MFMA16(fah[i], fbh[j], acc[i][j]);
    };
    STAGE(0, lds[0]);
    STAGE(1, lds[1]);
    for (int t = 0; t < nt; t += 3) {
        BODY(t, lds[0], lds[2]);
        if (t + 1 < nt) BODY(t + 1, lds[1], lds[0]);
        if (t + 2 < nt) BODY(t + 2, lds[2], lds[1]);
    }
    float* so = sc + (size_t)z * NN;
#pragma unroll
    for (int i = 0; i < 4; ++i)
#pragma unroll
        for (int j = 0; j < 4; ++j)
#pragma unroll
            for (int r = 0; r < 4; ++r) {
                int gi = byi * 128 + mb + i * 16 + (l >> 4) * 4 + r;
                int gk = bxk * 128 + nb + j * 16 + (l & 15);
                if (gk <= gi) so[(size_t)gi * 2048 + gk] = acc[i][j][r];
            }
}

// ---- row softmax (k<=i) -> bf16 attn, prefix-only loads -------------------------
__global__ __launch_bounds__(256) void k_softmax(const float* __restrict__ scb,
                                                 ushort_t* __restrict__ attn) {
    const int z = blockIdx.x >> 11, i = blockIdx.x & 2047;
    const float* scr = scb + (size_t)z * NN + (size_t)i * 2048;
    ushort_t* arow = attn + (size_t)z * NN + (size_t)i * 2048;
    const int tid = threadIdx.x, k0 = tid * 8;
    float sv[8];
    if (k0 <= i) {   // only read the valid prefix
        float4 a0 = *(const float4*)(scr + k0), a1 = *(const float4*)(scr + k0 + 4);
        sv[0] = a0.x; sv[1] = a0.y; sv[2] = a0.z; sv[3] = a0.w;
        sv[4] = a1.x; sv[5] = a1.y; sv[6] = a1.z; sv[7] = a1.w;
    } else {
#pragma unroll
        for (int e = 0; e < 8; ++e) sv[e] = -3e38f;
    }
    float s[8];
    float m = -3e38f;
#pragma unroll
    for (int e = 0; e < 8; ++e) {
        s[e] = (k0 + e <= i) ? sv[e] : -3e38f;
        m = fmaxf(m, s[e]);
    }
    __shared__ float red[256];
    red[tid] = m;
    __syncthreads();
    for (int ss = 128; ss; ss >>= 1) {
        if (tid < ss) red[tid] = fmaxf(red[tid], red[tid + ss]);
        __syncthreads();
    }
    m = red[0];
    __syncthreads();
    float p[8], sum = 0.f;
#pragma unroll
    for (int e = 0; e < 8; ++e) { p[e] = expf(s[e] - m); sum += p[e]; }
    red[tid] = sum;
    __syncthreads();
    for (int ss = 128; ss; ss >>= 1) {
        if (tid < ss) red[tid] += red[tid + ss];
        __syncthreads();
    }
    const float inv = 1.f / red[0];
    const int lim = ((i >> 7) + 1) << 7;
    if (k0 < lim) {
        short8 o;
#pragma unroll
        for (int e = 0; e < 8; ++e) o[e] = (short)f2b(p[e] * inv);
        *(short8*)(arow + k0) = o;
    }
}

// ---- pv: split-k partial O chunks (fp32 into sc area), unroll-3 static bufs -----
__global__ __launch_bounds__(256) void k_pv(const ushort_t* __restrict__ attn,
                                            const ushort_t* __restrict__ vcT,
                                            float* __restrict__ opbase, int g0) {
    const int z = blockIdx.x, hh = g0 + z;
    int pp = blockIdx.y, byi = 15, c;
    for (;;) {
        int cb = (byi >> 2) + 1;
        if (pp < cb) { c = pp; break; }
        pp -= cb;
        --byi;
    }
    const int nt = min(4, byi + 1 - c * 4) * 4;
    const ushort_t* ap = attn + (size_t)z * NN + (size_t)(byi * 128) * 2048 + c * 512;
    const ushort_t* vp = vcT + (size_t)hh * 131072 + c * 512;
    float* op = opbase + (size_t)z * NN + (size_t)(c * 2048) * 64;
    __shared__ __align__(16) ushort_t lds[3][6144];
    const int l = threadIdx.x & 63, w = threadIdx.x >> 6, mb = w * 32;
    auto STAGE = [&](int t, ushort_t* buf) {
        if (t >= nt) return;
        const int k0 = t * 32;
        for (int u = w * 3; u < w * 3 + 3; ++u) {
            if (u < 8) stage16(ap + k0, 2048, buf, u);
            else stage16(vp + k0, 2048, buf + 4096, u - 8);
        }
    };
    f32x4 acc[2][4] = {};
    auto BODY = [&](int t, const ushort_t* cur, ushort_t* stg) {
        if (t + 1 < nt) wait_vm3(); else wait_vm0();
        __builtin_amdgcn_s_barrier();
        STAGE(t + 2, stg);
        short8 fa[2], fb[4];
#pragma unroll
        for (int i = 0; i < 2; ++i) fa[i] = lfrag(cur, mb + i * 16, l);
#pragma unroll
        for (int j = 0; j < 4; ++j) fb[j] = lfrag(cur + 4096, j * 16, l);
#pragma unroll
        for (int i = 0; i < 2; ++i)
#pragma unroll
            for (int j = 0; j < 4; ++j) acc[i][j] = MFMA16(fa[i], fb[j], acc[i][j]);
    };
    STAGE(0, lds[0]);
    STAGE(1, lds[1]);
    for (int t = 0; t < nt; t += 3) {
        BODY(t, lds[0], lds[2]);
        if (t + 1 < nt) BODY(t + 1, lds[1], lds[0]);
        if (t + 2 < nt) BODY(t + 2, lds[2], lds[1]);
    }
#pragma unroll
    for (int i = 0; i < 2; ++i)
#pragma unroll
        for (int j = 0; j < 4; ++j)
#pragma unroll
            for (int r = 0; r < 4; ++r) {
                int gi = byi * 128 + mb + i * 16 + (l >> 4) * 4 + r;
                int dd = j * 16 + (l & 15);
                op[(size_t)gi * 64 + dd] = acc[i][j][r];
            }
}

// ---- pv combine: sum chunks -> bf16 attno ---------------------------------------
__global__ __launch_bounds__(256) void k_pvc(const float* __restrict__ opall,
                                             ushort_t* __restrict__ attno, int g0) {
    const int z = blockIdx.x >> 9, rem = blockIdx.x & 511;
    const int i = rem * 4 + (threadIdx.x >> 6), d = threadIdx.x & 63;
    const int hh = g0 + z, b = hh >> 3, h = hh & 7;
    const float* op = opall + (size_t)z * NN;
    const int nc = (i >> 9) + 1;
    float a = 0.f;
    for (int c = 0; c < nc; ++c) a += op[(size_t)(c * 2048 + i) * 64 + d];
    attno[(size_t)(b * 2048 + i) * 512 + h * 64 + d] = f2b(a);
}

// ---- final = attno @ Wout^T (single bf16), unroll-3 static bufs -----------------
__global__ __launch_bounds__(256) void k_outproj(const ushort_t* __restrict__ attno,
                                                 const ushort_t* __restrict__ woh,
                                                 float* __restrict__ out) {
    __shared__ __align__(16) ushort_t lds[3][8192];
    const int m0 = blockIdx.y * 128, n0 = blockIdx.x * 128;
    const int l = threadIdx.x & 63, w = threadIdx.x >> 6;
    const int mb = (w >> 1) * 64, nb = (w & 1) * 64;
    const ushort_t* pa = attno + (size_t)m0 * DI;
    const ushort_t* pb = woh + (size_t)n0 * DI;
    auto STAGE = [&](int t, ushort_t* buf) {
        if (t >= 16) return;
        const int k0 = t * 32;
        for (int u = w * 4; u < w * 4 + 4; ++u) {
            if (u < 8) stage16(pa + k0, DI, buf, u);
            else stage16(pb + k0, DI, buf + 4096, u - 8);
        }
    };
    f32x4 acc[4][4] = {};
    auto BODY = [&](int t, const ushort_t* cur, ushort_t* stg) {
        if (t + 1 < 16) wait_vm4(); else wait_vm0();
        __builtin_amdgcn_s_barrier();
        STAGE(t + 2, stg);
        short8 fa[4], fb[4];
#pragma unroll
        for (int i = 0; i < 4; ++i) fa[i] = lfrag(cur, mb + i * 16, l);
#pragma unroll
        for (int j = 0; j < 4; ++j) fb[j] = lfrag(cur + 4096, nb + j * 16, l);
#pragma unroll
        for (int i = 0; i < 4; ++i)
#pragma unroll
            for (int j = 0; j < 4; ++j) acc[i][j] = MFMA16(fa[i], fb[j], acc[i][j]);
    };
    STAGE(0, lds[0]);
    STAGE(1, lds[1]);
    for (int t = 0; t < 16; t += 3) {
        BODY(t, lds[0], lds[2]);
        if (t + 1 < 16) BODY(t + 1, lds[1], lds[0]);
        if (t + 2 < 16) BODY(t + 2, lds[2], lds[1]);
    }
#pragma unroll
    for (int i = 0; i < 4; ++i)
#pragma unroll
        for (int j = 0; j < 4; ++j)
#pragma unroll
            for (int r = 0; r < 4; ++r) {
                int m = m0 + mb + i * 16 + (l >> 4) * 4 + r;
                int n = n0 + nb + j * 16 + (l & 15);
                out[(size_t)m * DM + n] = acc[i][j][r];
            }
}

extern "C" void kernel_launch(void* const* d_in, const int* in_sizes, int n_in,
                              void* d_out, int out_size, void* d_ws, size_t ws_size,
                              hipStream_t stream) {
    const float* x = (const float*)d_in[0];
    const float* Wqkv = (const float*)d_in[1];
    const float* Wout = (const float*)d_in[2];
    float* out = (float*)d_out;

    const size_t fixedb = 33554432ull;          // qh + vcT + attno (bytes)
    const size_t perh = 26214400ull;            // Ph (8MB) + diag (1MB) + sc f32 (16MB)
    int g = 0;
    for (int cand : {16, 8, 4, 2, 1})
        if (fixedb + perh * (size_t)cand <= ws_size) { g = cand; break; }
    if (!g) return;

    ushort_t* qh = (ushort_t*)d_ws;          // 12,582,912 el
    ushort_t* vcT = qh + 12582912;           // 2,097,152 el
    ushort_t* attno = vcT + 2097152;         // 2,097,152 el
    ushort_t* pool = attno + 2097152;
    // cvt/proj phase aliases (dead after k_proj):
    ushort_t* xh = pool;                     // 4,194,304
    ushort_t* wh = xh + 4194304;             // 3,145,728
    // group phase:
    ushort_t* Ph = pool;                                  // g*NN (attn after softmax)
    ushort_t* t1dh = Ph + (size_t)g * NN;                 // g*262144
    ushort_t* lkdh = t1dh + (size_t)g * 262144;           // g*262144
    float* scf = (float*)(lkdh + (size_t)g * 262144);     // g*NN f32 (pv partials too)
    // outproj phase:
    ushort_t* woh = pool;

    k_cvt<<<dim3(1024), 256, 0, stream>>>((const float4*)x, xh, nullptr, 1048576, 0);
    k_cvt<<<dim3(1024), 256, 0, stream>>>((const float4*)Wqkv, wh, nullptr, 786432, 0);
    k_proj<<<dim3(24, 32), 256, 0, stream>>>(xh, wh, qh, vcT);

    for (int g0 = 0; g0 < 16; g0 += g) {
        k_tl<<<dim3(2 * g, 136), 256, 0, stream>>>(qh, Ph, t1dh, lkdh, g0);
        k_scores<<<dim3(g, 136), 256, 0, stream>>>(Ph, t1dh, lkdh, qh, scf, g0);
        k_softmax<<<dim3(2048 * g), 256, 0, stream>>>(scf, Ph);
        k_pv<<<dim3(g, 40), 256, 0, stream>>>(Ph, vcT, scf, g0);
        k_pvc<<<dim3(512 * g), 256, 0, stream>>>(scf, attno, g0);
    }

    k_cvt<<<dim3(512), 256, 0, stream>>>((const float4*)Wout, woh, nullptr, 131072, 0);
    k_outproj<<<dim3(8, 32), 256, 0, stream>>>(attno, woh, out);
}

// Round 21
// 349.999 us; speedup vs baseline: 1.0582x; 1.0582x over previous
//
#include <hip/hip_runtime.h>
#include <cmath>

typedef unsigned short ushort_t;
typedef __attribute__((ext_vector_type(8))) short short8;
typedef __attribute__((ext_vector_type(4))) float f32x4;
typedef __attribute__((ext_vector_type(4))) short short4v;

static constexpr int NSEQ = 2048, DM = 1024, DI = 512;
static constexpr size_t NN = (size_t)NSEQ * NSEQ;

__device__ __forceinline__ ushort_t f2b(float v) {
    unsigned u = __float_as_uint(v);
    return (ushort_t)((u + 0x7fffu + ((u >> 16) & 1u)) >> 16);  // RTNE
}
__device__ __forceinline__ float b2f(ushort_t b) { return __uint_as_float(((unsigned)b) << 16); }
__device__ __forceinline__ float sigm(float x) { return 1.f / (1.f + expf(-x)); }
__device__ __forceinline__ float silu(float x) { return x / (1.f + expf(-x)); }

#define MFMA16(a, b, c) __builtin_amdgcn_mfma_f32_16x16x32_bf16(a, b, c, 0, 0, 0)

// counted-vmcnt waits (T4): never drain to 0 mid-loop
__device__ __forceinline__ void wait_vm8() { asm volatile("s_waitcnt vmcnt(8)" ::: "memory"); }
__device__ __forceinline__ void wait_vm3() { asm volatile("s_waitcnt vmcnt(3)" ::: "memory"); }
__device__ __forceinline__ void wait_vm4() { asm volatile("s_waitcnt vmcnt(4)" ::: "memory"); }
__device__ __forceinline__ void wait_vm0() { asm volatile("s_waitcnt vmcnt(0)" ::: "memory"); }

// ---- async global->LDS staging, source pre-swizzled (rule #21) ------------------
__device__ __forceinline__ void gll16(const ushort_t* g, ushort_t* l) {
    __builtin_amdgcn_global_load_lds((const __attribute__((address_space(1))) void*)g,
                                     (__attribute__((address_space(3))) void*)l, 16, 0, 0);
}
__device__ __forceinline__ void stage16(const ushort_t* g, int ldg, ushort_t* lds, int q) {
    const int l = threadIdx.x & 63;
    const int row = l >> 2;
    const int ch = (l & 3) ^ ((l >> 3) & 3);
    gll16(g + (size_t)(q * 16 + row) * ldg + ch * 8, lds + q * 512);
}
__device__ __forceinline__ short8 lfrag(const ushort_t* t, int row0, int lane) {
    const int row = row0 + (lane & 15);
    const int ch = (lane >> 4) ^ ((row >> 1) & 3);
    return *(const short8*)(t + row * 32 + (ch << 3));
}
// descending-length triangular pair decode: p in [0,136) -> (lo, lo+d), d=15..0
__device__ __forceinline__ void pair_decode(int p, int& lo, int& d) {
    d = 15;
    int cnt = 1;
    while (p >= cnt) { p -= cnt; --d; cnt = 16 - d; }
    lo = p;
}

// ---- one-shot f32 -> bf16 hi(/lo) -----------------------------------------------
__global__ __launch_bounds__(256) void k_cvt(const float4* __restrict__ src,
                                             ushort_t* __restrict__ hi,
                                             ushort_t* __restrict__ lo, int n4, int has_lo) {
    for (int i = blockIdx.x * 256 + threadIdx.x; i < n4; i += gridDim.x * 256) {
        float4 f = src[i];
        float a[4] = {f.x, f.y, f.z, f.w};
        short4v hv, lv;
#pragma unroll
        for (int j = 0; j < 4; ++j) {
            ushort_t h = f2b(a[j]);
            hv[j] = (short)h;
            lv[j] = (short)f2b(a[j] - b2f(h));
        }
        *(short4v*)(hi + (size_t)i * 4) = hv;
        if (has_lo) *(short4v*)(lo + (size_t)i * 4) = lv;
    }
}

// ---- proj: qkv = x @ Wqkv^T (single bf16), 3-buf depth-2 counted-vmcnt ----------
__global__ __launch_bounds__(256) void k_proj(const ushort_t* __restrict__ xh,
                                              const ushort_t* __restrict__ wh,
                                              ushort_t* __restrict__ qh,
                                              ushort_t* __restrict__ vcT) {
    __shared__ __align__(16) ushort_t lds[3][8192];    // [A|B] 16KB/buf, 48KB total
    const int flat = blockIdx.x + 24 * blockIdx.y;
    const int p = (flat & 7) * 96 + (flat >> 3);
    const int bx = p % 24, by = p / 24;
    const int m0 = by * 128, n0 = bx * 128;
    const int l = threadIdx.x & 63, w = threadIdx.x >> 6;
    const int mb = (w >> 1) * 64, nb = (w & 1) * 64;
    const ushort_t* matA = xh + (size_t)m0 * DM;
    const ushort_t* matB = wh + (size_t)n0 * DM;
    const bool stager = (w == 0 || w == 1);
    auto STAGE = [&](int t, ushort_t* buf) {
        if (t >= 32 || !stager) return;
        const ushort_t* src = (w == 0) ? matA + t * 32 : matB + t * 32;
        ushort_t* dst = buf + ((w == 0) ? 0 : 4096);
        for (int q = 0; q < 8; ++q) stage16(src, DM, dst, q);
    };
    STAGE(0, lds[0]);
    STAGE(1, lds[1]);
    f32x4 acc[4][4] = {};
    for (int t = 0; t < 32; ++t) {
        if (t + 1 < 32 && stager) wait_vm8(); else wait_vm0();
        __builtin_amdgcn_s_barrier();   // buf t ready; mm(t-1) reads done
        STAGE(t + 2, lds[(t + 2) % 3]);
        const ushort_t* buf = lds[t % 3];
        short8 fah[4], fbh[4];
#pragma unroll
        for (int i = 0; i < 4; ++i) fah[i] = lfrag(buf, mb + i * 16, l);
#pragma unroll
        for (int j = 0; j < 4; ++j) fbh[j] = lfrag(buf + 4096, nb + j * 16, l);
#pragma unroll
        for (int i = 0; i < 4; ++i)
#pragma unroll
            for (int j = 0; j < 4; ++j) acc[i][j] = MFMA16(fah[i], fbh[j], acc[i][j]);
    }
#pragma unroll
    for (int i = 0; i < 4; ++i)
#pragma unroll
        for (int j = 0; j < 4; ++j)
#pragma unroll
            for (int r = 0; r < 4; ++r) {
                int m = m0 + mb + i * 16 + (l >> 4) * 4 + r;
                int n = n0 + nb + j * 16 + (l & 15);
                float v = acc[i][j][r];
                int tt = n >> 9, head = (n >> 6) & 7, dd = n & 63;
                int b = m >> 11, np = m & 2047;
                if (tt == 0 || tt == 3) v *= 0.125f;
                ushort_t h = f2b(v);
                size_t off = (size_t)(tt * 16 + b * 8 + head) * 131072 + (size_t)np * 64 + dd;
                qh[off] = h;
                if (tt == 5) vcT[(size_t)(b * 8 + head) * 131072 + (size_t)dd * 2048 + np] = h;
            }
}

// ---- tl: mode0 t1 = qc.vu^T (hi), mode1 look = sigm(qu.ku^T) (hi); 32KB LDS -----
__global__ __launch_bounds__(256) void k_tl(const ushort_t* __restrict__ qkvh,
                                            ushort_t* __restrict__ Ph,
                                            ushort_t* __restrict__ t1dh,
                                            ushort_t* __restrict__ lkdh, int g0) {
    const int mode = blockIdx.x & 1, z = blockIdx.x >> 1, hh = g0 + z;
    int lo_t, d;
    pair_decode(blockIdx.y, lo_t, d);
    const int by = mode ? lo_t : lo_t + d;      // mode0: by=i (>=bx); mode1: by=k (<=bx)
    const int bx = mode ? lo_t + d : lo_t;
    __shared__ __align__(16) ushort_t lds[2][8192];    // [A|B] 16KB/buf
    const int l = threadIdx.x & 63, w = threadIdx.x >> 6;
    const int mb = (w >> 1) * 64, nb = (w & 1) * 64;
    const int ta = mode ? 0 : 3, tb = mode ? 1 : 2;
    const ushort_t* matA = qkvh + (size_t)(ta * 16 + hh) * 131072 + (size_t)(by * 128) * 64;
    const ushort_t* matB = qkvh + (size_t)(tb * 16 + hh) * 131072 + (size_t)(bx * 128) * 64;
    auto STAGE = [&](int t, ushort_t* buf) {
        if (w == 0) for (int q = 0; q < 8; ++q) stage16(matA + t * 32, 64, buf, q);
        else if (w == 1) for (int q = 0; q < 8; ++q) stage16(matB + t * 32, 64, buf + 4096, q);
    };
    STAGE(0, lds[0]);
    __syncthreads();
    f32x4 acc[4][4] = {};
    for (int t = 0; t < 2; ++t) {
        if (t == 0) STAGE(1, lds[1]);
        const ushort_t* buf = lds[t & 1];
        short8 fah[4], fbh[4];
#pragma unroll
        for (int i = 0; i < 4; ++i) fah[i] = lfrag(buf, mb + i * 16, l);
#pragma unroll
        for (int j = 0; j < 4; ++j) fbh[j] = lfrag(buf + 4096, nb + j * 16, l);
#pragma unroll
        for (int i = 0; i < 4; ++i)
#pragma unroll
            for (int j = 0; j < 4; ++j) acc[i][j] = MFMA16(fah[i], fbh[j], acc[i][j]);
        __syncthreads();
    }
    const bool isdiag = (bx == by);
    ushort_t* ph = Ph + (size_t)z * NN;
    if (mode == 0) {
        ushort_t* dh = t1dh + ((size_t)z * 16 + by) * 16384;
#pragma unroll
        for (int i = 0; i < 4; ++i)
#pragma unroll
            for (int j = 0; j < 4; ++j)
#pragma unroll
                for (int r = 0; r < 4; ++r) {
                    int gi = by * 128 + mb + i * 16 + (l >> 4) * 4 + r;
                    int gj = bx * 128 + nb + j * 16 + (l & 15);
                    ushort_t h = f2b(acc[i][j][r]);
                    if (gj <= gi) ph[(size_t)gi * 2048 + gj] = h;
                    if (isdiag) dh[(gi & 127) * 128 + (gj & 127)] = (gj <= gi) ? h : 0;
                }
    } else {
        ushort_t* dh = lkdh + ((size_t)z * 16 + by) * 16384;
#pragma unroll
        for (int i = 0; i < 4; ++i)
#pragma unroll
            for (int j = 0; j < 4; ++j)
#pragma unroll
                for (int r = 0; r < 4; ++r) {
                    int gk = by * 128 + mb + i * 16 + (l >> 4) * 4 + r;
                    int gj = bx * 128 + nb + j * 16 + (l & 15);
                    ushort_t h = f2b(sigm(acc[i][j][r]));
                    if (gj > gk) ph[(size_t)gk * 2048 + gj] = h;
                    if (isdiag) dh[(gk & 127) * 128 + (gj & 127)] = (gj > gk) ? h : 0;
                }
    }
}

// ---- scores: Su mm16 + Sc mm16, 3x16KB buffers [A|B], depth-2 pipeline ----------
__global__ __launch_bounds__(256) void k_scores(const ushort_t* __restrict__ Ph,
                                                const ushort_t* __restrict__ t1dh,
                                                const ushort_t* __restrict__ lkdh,
                                                const ushort_t* __restrict__ qkvh,
                                                float* __restrict__ sc, int g0) {
    const int z = blockIdx.x, hh = g0 + z;
    int bxk, d;
    pair_decode(blockIdx.y, bxk, d);
    const int byi = bxk + d;
    __shared__ __align__(16) ushort_t lds[3][8192];   // [A|B] 16KB/buf, 48KB total
    const int l = threadIdx.x & 63, w = threadIdx.x >> 6;
    const int mb = (w >> 1) * 64, nb = (w & 1) * 64;
    const int nsu = (d + 1) * 4, nt = nsu + 2;
    const ushort_t* pAh = Ph + (size_t)z * NN + (size_t)(byi * 128) * 2048;
    const ushort_t* pBh = Ph + (size_t)z * NN + (size_t)(bxk * 128) * 2048;
    const ushort_t* dAh = t1dh + ((size_t)z * 16 + byi) * 16384;
    const ushort_t* dBh = lkdh + ((size_t)z * 16 + bxk) * 16384;
    const ushort_t* qch = qkvh + (size_t)(3 * 16 + hh) * 131072 + (size_t)(byi * 128) * 64;
    const ushort_t* kch = qkvh + (size_t)(4 * 16 + hh) * 131072 + (size_t)(bxk * 128) * 64;
    const bool stager = (w == 0 || w == 2);
    auto STAGE = [&](int t, ushort_t* buf) {
        if (t >= nt || !stager) return;
        const ushort_t* src;
        int ld;
        if (t < nsu) {
            const int tb = t >> 2, kloc = (t & 3) * 32;
            if (w == 0) {
                if (tb == d) { src = dAh + kloc; ld = 128; }
                else { src = pAh + (bxk + tb) * 128 + kloc; ld = 2048; }
            } else {
                if (tb == 0) { src = dBh + kloc; ld = 128; }
                else { src = pBh + (bxk + tb) * 128 + kloc; ld = 2048; }
            }
        } else {
            const int k0 = (t - nsu) * 32;
            src = (w == 0) ? qch + k0 : kch + k0;
            ld = 64;
        }
        ushort_t* dst = buf + ((w == 0) ? 0 : 4096);
        for (int q = 0; q < 8; ++q) stage16(src, ld, dst, q);
    };
    STAGE(0, lds[0]);
    STAGE(1, lds[1]);
    f32x4 acc[4][4] = {};
    for (int t = 0; t < nt; ++t) {
        if (t + 1 < nt && stager) wait_vm8(); else wait_vm0();
        __builtin_amdgcn_s_barrier();   // buf t ready; mm(t-1) reads done
        STAGE(t + 2, lds[(t + 2) % 3]);
        if (t == nsu) {
#pragma unroll
            for (int i = 0; i < 4; ++i)
#pragma unroll
                for (int j = 0; j < 4; ++j)
#pragma unroll
                    for (int r = 0; r < 4; ++r) acc[i][j][r] = -silu(acc[i][j][r]);
        }
        const ushort_t* buf = lds[t % 3];
        short8 fah[4], fbh[4];
#pragma unroll
        for (int i = 0; i < 4; ++i) fah[i] = lfrag(buf, mb + i * 16, l);
#pragma unroll
        for (int j = 0; j < 4; ++j) fbh[j] = lfrag(buf + 4096, nb + j * 16, l);
#pragma unroll
        for (int i = 0; i < 4; ++i)
#pragma unroll
            for (int j = 0; j < 4; ++j) acc[i][j] = MFMA16(fah[i], fbh[j], acc[i][j]);
    }
    float* so = sc + (size_t)z * NN;
#pragma unroll
    for (int i = 0; i < 4; ++i)
#pragma unroll
        for (int j = 0; j < 4; ++j)
#pragma unroll
            for (int r = 0; r < 4; ++r) {
                int gi = byi * 128 + mb + i * 16 + (l >> 4) * 4 + r;
                int gk = bxk * 128 + nb + j * 16 + (l & 15);
                if (gk <= gi) so[(size_t)gi * 2048 + gk] = acc[i][j][r];
            }
}

// ---- row softmax (k<=i) -> bf16 attn, prefix-only loads -------------------------
__global__ __launch_bounds__(256) void k_softmax(const float* __restrict__ scb,
                                                 ushort_t* __restrict__ attn) {
    const int z = blockIdx.x >> 11, i = blockIdx.x & 2047;
    const float* scr = scb + (size_t)z * NN + (size_t)i * 2048;
    ushort_t* arow = attn + (size_t)z * NN + (size_t)i * 2048;
    const int tid = threadIdx.x, k0 = tid * 8;
    float sv[8];
    if (k0 <= i) {   // only read the valid prefix
        float4 a0 = *(const float4*)(scr + k0), a1 = *(const float4*)(scr + k0 + 4);
        sv[0] = a0.x; sv[1] = a0.y; sv[2] = a0.z; sv[3] = a0.w;
        sv[4] = a1.x; sv[5] = a1.y; sv[6] = a1.z; sv[7] = a1.w;
    } else {
#pragma unroll
        for (int e = 0; e < 8; ++e) sv[e] = -3e38f;
    }
    float s[8];
    float m = -3e38f;
#pragma unroll
    for (int e = 0; e < 8; ++e) {
        s[e] = (k0 + e <= i) ? sv[e] : -3e38f;
        m = fmaxf(m, s[e]);
    }
    __shared__ float red[256];
    red[tid] = m;
    __syncthreads();
    for (int ss = 128; ss; ss >>= 1) {
        if (tid < ss) red[tid] = fmaxf(red[tid], red[tid + ss]);
        __syncthreads();
    }
    m = red[0];
    __syncthreads();
    float p[8], sum = 0.f;
#pragma unroll
    for (int e = 0; e < 8; ++e) { p[e] = expf(s[e] - m); sum += p[e]; }
    red[tid] = sum;
    __syncthreads();
    for (int ss = 128; ss; ss >>= 1) {
        if (tid < ss) red[tid] += red[tid + ss];
        __syncthreads();
    }
    const float inv = 1.f / red[0];
    const int lim = ((i >> 7) + 1) << 7;
    if (k0 < lim) {
        short8 o;
#pragma unroll
        for (int e = 0; e < 8; ++e) o[e] = (short)f2b(p[e] * inv);
        *(short8*)(arow + k0) = o;
    }
}

// ---- pv: split-k partial O chunks (fp32 into sc area), 3-buf pipeline -----------
__global__ __launch_bounds__(256) void k_pv(const ushort_t* __restrict__ attn,
                                            const ushort_t* __restrict__ vcT,
                                            float* __restrict__ opbase, int g0) {
    const int z = blockIdx.x, hh = g0 + z;
    int pp = blockIdx.y, byi = 15, c;
    for (;;) {
        int cb = (byi >> 2) + 1;
        if (pp < cb) { c = pp; break; }
        pp -= cb;
        --byi;
    }
    const int nt = min(4, byi + 1 - c * 4) * 4;
    const ushort_t* ap = attn + (size_t)z * NN + (size_t)(byi * 128) * 2048 + c * 512;
    const ushort_t* vp = vcT + (size_t)hh * 131072 + c * 512;
    float* op = opbase + (size_t)z * NN + (size_t)(c * 2048) * 64;
    __shared__ __align__(16) ushort_t lds[3][6144];
    const int l = threadIdx.x & 63, w = threadIdx.x >> 6, mb = w * 32;
    auto STAGE = [&](int t, ushort_t* buf) {
        if (t >= nt) return;
        const int k0 = t * 32;
        for (int u = w * 3; u < w * 3 + 3; ++u) {
            if (u < 8) stage16(ap + k0, 2048, buf, u);
            else stage16(vp + k0, 2048, buf + 4096, u - 8);
        }
    };
    STAGE(0, lds[0]);
    STAGE(1, lds[1]);
    f32x4 acc[2][4] = {};
    for (int t = 0; t < nt; ++t) {
        if (t + 1 < nt) wait_vm3(); else wait_vm0();
        __builtin_amdgcn_s_barrier();
        STAGE(t + 2, lds[(t + 2) % 3]);
        const ushort_t* buf = lds[t % 3];
        short8 fa[2], fb[4];
#pragma unroll
        for (int i = 0; i < 2; ++i) fa[i] = lfrag(buf, mb + i * 16, l);
#pragma unroll
        for (int j = 0; j < 4; ++j) fb[j] = lfrag(buf + 4096, j * 16, l);
#pragma unroll
        for (int i = 0; i < 2; ++i)
#pragma unroll
            for (int j = 0; j < 4; ++j) acc[i][j] = MFMA16(fa[i], fb[j], acc[i][j]);
    }
#pragma unroll
    for (int i = 0; i < 2; ++i)
#pragma unroll
        for (int j = 0; j < 4; ++j)
#pragma unroll
            for (int r = 0; r < 4; ++r) {
                int gi = byi * 128 + mb + i * 16 + (l >> 4) * 4 + r;
                int dd = j * 16 + (l & 15);
                op[(size_t)gi * 64 + dd] = acc[i][j][r];
            }
}

// ---- pv combine: sum chunks -> bf16 attno ---------------------------------------
__global__ __launch_bounds__(256) void k_pvc(const float* __restrict__ opall,
                                             ushort_t* __restrict__ attno, int g0) {
    const int z = blockIdx.x >> 9, rem = blockIdx.x & 511;
    const int i = rem * 4 + (threadIdx.x >> 6), d = threadIdx.x & 63;
    const int hh = g0 + z, b = hh >> 3, h = hh & 7;
    const float* op = opall + (size_t)z * NN;
    const int nc = (i >> 9) + 1;
    float a = 0.f;
    for (int c = 0; c < nc; ++c) a += op[(size_t)(c * 2048 + i) * 64 + d];
    attno[(size_t)(b * 2048 + i) * 512 + h * 64 + d] = f2b(a);
}

// ---- final = attno @ Wout^T (single bf16), 3-buf pipeline -----------------------
__global__ __launch_bounds__(256) void k_outproj(const ushort_t* __restrict__ attno,
                                                 const ushort_t* __restrict__ woh,
                                                 float* __restrict__ out) {
    __shared__ __align__(16) ushort_t lds[3][8192];
    const int m0 = blockIdx.y * 128, n0 = blockIdx.x * 128;
    const int l = threadIdx.x & 63, w = threadIdx.x >> 6;
    const int mb = (w >> 1) * 64, nb = (w & 1) * 64;
    const ushort_t* pa = attno + (size_t)m0 * DI;
    const ushort_t* pb = woh + (size_t)n0 * DI;
    auto STAGE = [&](int t, ushort_t* buf) {
        if (t >= 16) return;
        const int k0 = t * 32;
        for (int u = w * 4; u < w * 4 + 4; ++u) {
            if (u < 8) stage16(pa + k0, DI, buf, u);
            else stage16(pb + k0, DI, buf + 4096, u - 8);
        }
    };
    STAGE(0, lds[0]);
    STAGE(1, lds[1]);
    f32x4 acc[4][4] = {};
    for (int t = 0; t < 16; ++t) {
        if (t + 1 < 16) wait_vm4(); else wait_vm0();
        __builtin_amdgcn_s_barrier();
        STAGE(t + 2, lds[(t + 2) % 3]);
        const ushort_t* buf = lds[t % 3];
        short8 fa[4], fb[4];
#pragma unroll
        for (int i = 0; i < 4; ++i) fa[i] = lfrag(buf, mb + i * 16, l);
#pragma unroll
        for (int j = 0; j < 4; ++j) fb[j] = lfrag(buf + 4096, nb + j * 16, l);
#pragma unroll
        for (int i = 0; i < 4; ++i)
#pragma unroll
            for (int j = 0; j < 4; ++j) acc[i][j] = MFMA16(fa[i], fb[j], acc[i][j]);
    }
#pragma unroll
    for (int i = 0; i < 4; ++i)
#pragma unroll
        for (int j = 0; j < 4; ++j)
#pragma unroll
            for (int r = 0; r < 4; ++r) {
                int m = m0 + mb + i * 16 + (l >> 4) * 4 + r;
                int n = n0 + nb + j * 16 + (l & 15);
                out[(size_t)m * DM + n] = acc[i][j][r];
            }
}

extern "C" void kernel_launch(void* const* d_in, const int* in_sizes, int n_in,
                              void* d_out, int out_size, void* d_ws, size_t ws_size,
                              hipStream_t stream) {
    const float* x = (const float*)d_in[0];
    const float* Wqkv = (const float*)d_in[1];
    const float* Wout = (const float*)d_in[2];
    float* out = (float*)d_out;

    const size_t fixedb = 33554432ull;          // qh + vcT + attno (bytes)
    const size_t perh = 26214400ull;            // Ph (8MB) + diag (1MB) + sc f32 (16MB)
    int g = 0;
    for (int cand : {16, 8, 4, 2, 1})
        if (fixedb + perh * (size_t)cand <= ws_size) { g = cand; break; }
    if (!g) return;

    ushort_t* qh = (ushort_t*)d_ws;          // 12,582,912 el
    ushort_t* vcT = qh + 12582912;           // 2,097,152 el
    ushort_t* attno = vcT + 2097152;         // 2,097,152 el
    ushort_t* pool = attno + 2097152;
    // cvt/proj phase aliases (dead after k_proj):
    ushort_t* xh = pool;                     // 4,194,304
    ushort_t* wh = xh + 4194304;             // 3,145,728
    // group phase:
    ushort_t* Ph = pool;                                  // g*NN (attn after softmax)
    ushort_t* t1dh = Ph + (size_t)g * NN;                 // g*262144
    ushort_t* lkdh = t1dh + (size_t)g * 262144;           // g*262144
    float* scf = (float*)(lkdh + (size_t)g * 262144);     // g*NN f32 (pv partials too)
    // outproj phase:
    ushort_t* woh = pool;

    k_cvt<<<dim3(1024), 256, 0, stream>>>((const float4*)x, xh, nullptr, 1048576, 0);
    k_cvt<<<dim3(1024), 256, 0, stream>>>((const float4*)Wqkv, wh, nullptr, 786432, 0);
    k_proj<<<dim3(24, 32), 256, 0, stream>>>(xh, wh, qh, vcT);

    for (int g0 = 0; g0 < 16; g0 += g) {
        k_tl<<<dim3(2 * g, 136), 256, 0, stream>>>(qh, Ph, t1dh, lkdh, g0);
        k_scores<<<dim3(g, 136), 256, 0, stream>>>(Ph, t1dh, lkdh, qh, scf, g0);
        k_softmax<<<dim3(2048 * g), 256, 0, stream>>>(scf, Ph);
        k_pv<<<dim3(g, 40), 256, 0, stream>>>(Ph, vcT, scf, g0);
        k_pvc<<<dim3(512 * g), 256, 0, stream>>>(scf, attno, g0);
    }

    k_cvt<<<dim3(512), 256, 0, stream>>>((const float4*)Wout, woh, nullptr, 131072, 0);
    k_outproj<<<dim3(8, 32), 256, 0, stream>>>(attno, woh, out);
}

// Round 22
// 348.857 us; speedup vs baseline: 1.0617x; 1.0033x over previous
//
#include <hip/hip_runtime.h>
#include <cmath>

typedef unsigned short ushort_t;
typedef __attribute__((ext_vector_type(8))) short short8;
typedef __attribute__((ext_vector_type(4))) float f32x4;
typedef __attribute__((ext_vector_type(4))) short short4v;

static constexpr int NSEQ = 2048, DM = 1024, DI = 512;
static constexpr size_t NN = (size_t)NSEQ * NSEQ;

__device__ __forceinline__ ushort_t f2b(float v) {
    unsigned u = __float_as_uint(v);
    return (ushort_t)((u + 0x7fffu + ((u >> 16) & 1u)) >> 16);  // RTNE
}
__device__ __forceinline__ float b2f(ushort_t b) { return __uint_as_float(((unsigned)b) << 16); }
__device__ __forceinline__ float sigm(float x) { return 1.f / (1.f + expf(-x)); }
__device__ __forceinline__ float silu(float x) { return x / (1.f + expf(-x)); }

#define MFMA16(a, b, c) __builtin_amdgcn_mfma_f32_16x16x32_bf16(a, b, c, 0, 0, 0)

// counted-vmcnt waits (T4): never drain to 0 mid-loop
__device__ __forceinline__ void wait_vm8() { asm volatile("s_waitcnt vmcnt(8)" ::: "memory"); }
__device__ __forceinline__ void wait_vm3() { asm volatile("s_waitcnt vmcnt(3)" ::: "memory"); }
__device__ __forceinline__ void wait_vm4() { asm volatile("s_waitcnt vmcnt(4)" ::: "memory"); }
__device__ __forceinline__ void wait_vm0() { asm volatile("s_waitcnt vmcnt(0)" ::: "memory"); }

// ---- async global->LDS staging, source pre-swizzled (rule #21) ------------------
__device__ __forceinline__ void gll16(const ushort_t* g, ushort_t* l) {
    __builtin_amdgcn_global_load_lds((const __attribute__((address_space(1))) void*)g,
                                     (__attribute__((address_space(3))) void*)l, 16, 0, 0);
}
__device__ __forceinline__ void stage16(const ushort_t* g, int ldg, ushort_t* lds, int q) {
    const int l = threadIdx.x & 63;
    const int row = l >> 2;
    const int ch = (l & 3) ^ ((l >> 3) & 3);
    gll16(g + (size_t)(q * 16 + row) * ldg + ch * 8, lds + q * 512);
}
__device__ __forceinline__ short8 lfrag(const ushort_t* t, int row0, int lane) {
    const int row = row0 + (lane & 15);
    const int ch = (lane >> 4) ^ ((row >> 1) & 3);
    return *(const short8*)(t + row * 32 + (ch << 3));
}
// descending-length triangular pair decode: p in [0,136) -> (lo, lo+d), d=15..0
__device__ __forceinline__ void pair_decode(int p, int& lo, int& d) {
    d = 15;
    int cnt = 1;
    while (p >= cnt) { p -= cnt; --d; cnt = 16 - d; }
    lo = p;
}

// ---- one-shot f32 -> bf16 hi(/lo) -----------------------------------------------
__global__ __launch_bounds__(256) void k_cvt(const float4* __restrict__ src,
                                             ushort_t* __restrict__ hi,
                                             ushort_t* __restrict__ lo, int n4, int has_lo) {
    for (int i = blockIdx.x * 256 + threadIdx.x; i < n4; i += gridDim.x * 256) {
        float4 f = src[i];
        float a[4] = {f.x, f.y, f.z, f.w};
        short4v hv, lv;
#pragma unroll
        for (int j = 0; j < 4; ++j) {
            ushort_t h = f2b(a[j]);
            hv[j] = (short)h;
            lv[j] = (short)f2b(a[j] - b2f(h));
        }
        *(short4v*)(hi + (size_t)i * 4) = hv;
        if (has_lo) *(short4v*)(lo + (size_t)i * 4) = lv;
    }
}

// ---- proj: qkv = x @ Wqkv^T (single bf16), 3-buf depth-2, 4-wave staging --------
__global__ __launch_bounds__(256) void k_proj(const ushort_t* __restrict__ xh,
                                              const ushort_t* __restrict__ wh,
                                              ushort_t* __restrict__ qh,
                                              ushort_t* __restrict__ vcT) {
    __shared__ __align__(16) ushort_t lds[3][8192];    // [A|B] 16KB/buf, 48KB total
    const int flat = blockIdx.x + 24 * blockIdx.y;
    const int p = (flat & 7) * 96 + (flat >> 3);
    const int bx = p % 24, by = p / 24;
    const int m0 = by * 128, n0 = bx * 128;
    const int l = threadIdx.x & 63, w = threadIdx.x >> 6;
    const int mb = (w >> 1) * 64, nb = (w & 1) * 64;
    const ushort_t* matA = xh + (size_t)m0 * DM;
    const ushort_t* matB = wh + (size_t)n0 * DM;
    // 4-wave staging: wave w stages half (w>>1), chunks (w&1)*4..+4 -> 4 loads/wave
    auto STAGE = [&](int t, ushort_t* buf) {
        if (t >= 32) return;
        const bool ahalf = ((w >> 1) == 0);
        const ushort_t* src = ahalf ? matA + t * 32 : matB + t * 32;
        ushort_t* dst = buf + (ahalf ? 0 : 4096);
        const int q0 = (w & 1) * 4;
        for (int q = q0; q < q0 + 4; ++q) stage16(src, DM, dst, q);
    };
    STAGE(0, lds[0]);
    STAGE(1, lds[1]);
    f32x4 acc[4][4] = {};
    for (int t = 0; t < 32; ++t) {
        if (t + 1 < 32) wait_vm4(); else wait_vm0();
        __builtin_amdgcn_s_barrier();   // buf t ready; mm(t-1) reads done
        STAGE(t + 2, lds[(t + 2) % 3]);
        const ushort_t* buf = lds[t % 3];
        short8 fah[4], fbh[4];
#pragma unroll
        for (int i = 0; i < 4; ++i) fah[i] = lfrag(buf, mb + i * 16, l);
#pragma unroll
        for (int j = 0; j < 4; ++j) fbh[j] = lfrag(buf + 4096, nb + j * 16, l);
#pragma unroll
        for (int i = 0; i < 4; ++i)
#pragma unroll
            for (int j = 0; j < 4; ++j) acc[i][j] = MFMA16(fah[i], fbh[j], acc[i][j]);
    }
#pragma unroll
    for (int i = 0; i < 4; ++i)
#pragma unroll
        for (int j = 0; j < 4; ++j)
#pragma unroll
            for (int r = 0; r < 4; ++r) {
                int m = m0 + mb + i * 16 + (l >> 4) * 4 + r;
                int n = n0 + nb + j * 16 + (l & 15);
                float v = acc[i][j][r];
                int tt = n >> 9, head = (n >> 6) & 7, dd = n & 63;
                int b = m >> 11, np = m & 2047;
                if (tt == 0 || tt == 3) v *= 0.125f;
                ushort_t h = f2b(v);
                size_t off = (size_t)(tt * 16 + b * 8 + head) * 131072 + (size_t)np * 64 + dd;
                qh[off] = h;
                if (tt == 5) vcT[(size_t)(b * 8 + head) * 131072 + (size_t)dd * 2048 + np] = h;
            }
}

// ---- tl: mode0 t1 = qc.vu^T (hi), mode1 look = sigm(qu.ku^T) (hi); 32KB LDS -----
__global__ __launch_bounds__(256) void k_tl(const ushort_t* __restrict__ qkvh,
                                            ushort_t* __restrict__ Ph,
                                            ushort_t* __restrict__ t1dh,
                                            ushort_t* __restrict__ lkdh, int g0) {
    const int mode = blockIdx.x & 1, z = blockIdx.x >> 1, hh = g0 + z;
    int lo_t, d;
    pair_decode(blockIdx.y, lo_t, d);
    const int by = mode ? lo_t : lo_t + d;      // mode0: by=i (>=bx); mode1: by=k (<=bx)
    const int bx = mode ? lo_t + d : lo_t;
    __shared__ __align__(16) ushort_t lds[2][8192];    // [A|B] 16KB/buf
    const int l = threadIdx.x & 63, w = threadIdx.x >> 6;
    const int mb = (w >> 1) * 64, nb = (w & 1) * 64;
    const int ta = mode ? 0 : 3, tb = mode ? 1 : 2;
    const ushort_t* matA = qkvh + (size_t)(ta * 16 + hh) * 131072 + (size_t)(by * 128) * 64;
    const ushort_t* matB = qkvh + (size_t)(tb * 16 + hh) * 131072 + (size_t)(bx * 128) * 64;
    auto STAGE = [&](int t, ushort_t* buf) {
        if (w == 0) for (int q = 0; q < 8; ++q) stage16(matA + t * 32, 64, buf, q);
        else if (w == 1) for (int q = 0; q < 8; ++q) stage16(matB + t * 32, 64, buf + 4096, q);
    };
    STAGE(0, lds[0]);
    __syncthreads();
    f32x4 acc[4][4] = {};
    for (int t = 0; t < 2; ++t) {
        if (t == 0) STAGE(1, lds[1]);
        const ushort_t* buf = lds[t & 1];
        short8 fah[4], fbh[4];
#pragma unroll
        for (int i = 0; i < 4; ++i) fah[i] = lfrag(buf, mb + i * 16, l);
#pragma unroll
        for (int j = 0; j < 4; ++j) fbh[j] = lfrag(buf + 4096, nb + j * 16, l);
#pragma unroll
        for (int i = 0; i < 4; ++i)
#pragma unroll
            for (int j = 0; j < 4; ++j) acc[i][j] = MFMA16(fah[i], fbh[j], acc[i][j]);
        __syncthreads();
    }
    const bool isdiag = (bx == by);
    ushort_t* ph = Ph + (size_t)z * NN;
    if (mode == 0) {
        ushort_t* dh = t1dh + ((size_t)z * 16 + by) * 16384;
#pragma unroll
        for (int i = 0; i < 4; ++i)
#pragma unroll
            for (int j = 0; j < 4; ++j)
#pragma unroll
                for (int r = 0; r < 4; ++r) {
                    int gi = by * 128 + mb + i * 16 + (l >> 4) * 4 + r;
                    int gj = bx * 128 + nb + j * 16 + (l & 15);
                    ushort_t h = f2b(acc[i][j][r]);
                    if (gj <= gi) ph[(size_t)gi * 2048 + gj] = h;
                    if (isdiag) dh[(gi & 127) * 128 + (gj & 127)] = (gj <= gi) ? h : 0;
                }
    } else {
        ushort_t* dh = lkdh + ((size_t)z * 16 + by) * 16384;
#pragma unroll
        for (int i = 0; i < 4; ++i)
#pragma unroll
            for (int j = 0; j < 4; ++j)
#pragma unroll
                for (int r = 0; r < 4; ++r) {
                    int gk = by * 128 + mb + i * 16 + (l >> 4) * 4 + r;
                    int gj = bx * 128 + nb + j * 16 + (l & 15);
                    ushort_t h = f2b(sigm(acc[i][j][r]));
                    if (gj > gk) ph[(size_t)gk * 2048 + gj] = h;
                    if (isdiag) dh[(gk & 127) * 128 + (gj & 127)] = (gj > gk) ? h : 0;
                }
    }
}

// ---- scores: Su mm16 + Sc mm16, 3x16KB buffers, 4-wave staging ------------------
__global__ __launch_bounds__(256) void k_scores(const ushort_t* __restrict__ Ph,
                                                const ushort_t* __restrict__ t1dh,
                                                const ushort_t* __restrict__ lkdh,
                                                const ushort_t* __restrict__ qkvh,
                                                float* __restrict__ sc, int g0) {
    const int z = blockIdx.x, hh = g0 + z;
    int bxk, d;
    pair_decode(blockIdx.y, bxk, d);
    const int byi = bxk + d;
    __shared__ __align__(16) ushort_t lds[3][8192];   // [A|B] 16KB/buf, 48KB total
    const int l = threadIdx.x & 63, w = threadIdx.x >> 6;
    const int mb = (w >> 1) * 64, nb = (w & 1) * 64;
    const int nsu = (d + 1) * 4, nt = nsu + 2;
    const ushort_t* pAh = Ph + (size_t)z * NN + (size_t)(byi * 128) * 2048;
    const ushort_t* pBh = Ph + (size_t)z * NN + (size_t)(bxk * 128) * 2048;
    const ushort_t* dAh = t1dh + ((size_t)z * 16 + byi) * 16384;
    const ushort_t* dBh = lkdh + ((size_t)z * 16 + bxk) * 16384;
    const ushort_t* qch = qkvh + (size_t)(3 * 16 + hh) * 131072 + (size_t)(byi * 128) * 64;
    const ushort_t* kch = qkvh + (size_t)(4 * 16 + hh) * 131072 + (size_t)(bxk * 128) * 64;
    // 4-wave staging: wave w stages half (w>>1), chunks (w&1)*4..+4 -> 4 loads/wave
    auto STAGE = [&](int t, ushort_t* buf) {
        if (t >= nt) return;
        const bool ahalf = ((w >> 1) == 0);
        const ushort_t* src;
        int ld;
        if (t < nsu) {
            const int tb = t >> 2, kloc = (t & 3) * 32;
            if (ahalf) {
                if (tb == d) { src = dAh + kloc; ld = 128; }
                else { src = pAh + (bxk + tb) * 128 + kloc; ld = 2048; }
            } else {
                if (tb == 0) { src = dBh + kloc; ld = 128; }
                else { src = pBh + (bxk + tb) * 128 + kloc; ld = 2048; }
            }
        } else {
            const int k0 = (t - nsu) * 32;
            src = ahalf ? qch + k0 : kch + k0;
            ld = 64;
        }
        ushort_t* dst = buf + (ahalf ? 0 : 4096);
        const int q0 = (w & 1) * 4;
        for (int q = q0; q < q0 + 4; ++q) stage16(src, ld, dst, q);
    };
    STAGE(0, lds[0]);
    STAGE(1, lds[1]);
    f32x4 acc[4][4] = {};
    for (int t = 0; t < nt; ++t) {
        if (t + 1 < nt) wait_vm4(); else wait_vm0();
        __builtin_amdgcn_s_barrier();   // buf t ready; mm(t-1) reads done
        STAGE(t + 2, lds[(t + 2) % 3]);
        if (t == nsu) {
#pragma unroll
            for (int i = 0; i < 4; ++i)
#pragma unroll
                for (int j = 0; j < 4; ++j)
#pragma unroll
                    for (int r = 0; r < 4; ++r) acc[i][j][r] = -silu(acc[i][j][r]);
        }
        const ushort_t* buf = lds[t % 3];
        short8 fah[4], fbh[4];
#pragma unroll
        for (int i = 0; i < 4; ++i) fah[i] = lfrag(buf, mb + i * 16, l);
#pragma unroll
        for (int j = 0; j < 4; ++j) fbh[j] = lfrag(buf + 4096, nb + j * 16, l);
#pragma unroll
        for (int i = 0; i < 4; ++i)
#pragma unroll
            for (int j = 0; j < 4; ++j) acc[i][j] = MFMA16(fah[i], fbh[j], acc[i][j]);
    }
    float* so = sc + (size_t)z * NN;
#pragma unroll
    for (int i = 0; i < 4; ++i)
#pragma unroll
        for (int j = 0; j < 4; ++j)
#pragma unroll
            for (int r = 0; r < 4; ++r) {
                int gi = byi * 128 + mb + i * 16 + (l >> 4) * 4 + r;
                int gk = bxk * 128 + nb + j * 16 + (l & 15);
                if (gk <= gi) so[(size_t)gi * 2048 + gk] = acc[i][j][r];
            }
}

// ---- row softmax (k<=i) -> bf16 attn, prefix-only loads -------------------------
__global__ __launch_bounds__(256) void k_softmax(const float* __restrict__ scb,
                                                 ushort_t* __restrict__ attn) {
    const int z = blockIdx.x >> 11, i = blockIdx.x & 2047;
    const float* scr = scb + (size_t)z * NN + (size_t)i * 2048;
    ushort_t* arow = attn + (size_t)z * NN + (size_t)i * 2048;
    const int tid = threadIdx.x, k0 = tid * 8;
    float sv[8];
    if (k0 <= i) {   // only read the valid prefix
        float4 a0 = *(const float4*)(scr + k0), a1 = *(const float4*)(scr + k0 + 4);
        sv[0] = a0.x; sv[1] = a0.y; sv[2] = a0.z; sv[3] = a0.w;
        sv[4] = a1.x; sv[5] = a1.y; sv[6] = a1.z; sv[7] = a1.w;
    } else {
#pragma unroll
        for (int e = 0; e < 8; ++e) sv[e] = -3e38f;
    }
    float s[8];
    float m = -3e38f;
#pragma unroll
    for (int e = 0; e < 8; ++e) {
        s[e] = (k0 + e <= i) ? sv[e] : -3e38f;
        m = fmaxf(m, s[e]);
    }
    __shared__ float red[256];
    red[tid] = m;
    __syncthreads();
    for (int ss = 128; ss; ss >>= 1) {
        if (tid < ss) red[tid] = fmaxf(red[tid], red[tid + ss]);
        __syncthreads();
    }
    m = red[0];
    __syncthreads();
    float p[8], sum = 0.f;
#pragma unroll
    for (int e = 0; e < 8; ++e) { p[e] = expf(s[e] - m); sum += p[e]; }
    red[tid] = sum;
    __syncthreads();
    for (int ss = 128; ss; ss >>= 1) {
        if (tid < ss) red[tid] += red[tid + ss];
        __syncthreads();
    }
    const float inv = 1.f / red[0];
    const int lim = ((i >> 7) + 1) << 7;
    if (k0 < lim) {
        short8 o;
#pragma unroll
        for (int e = 0; e < 8; ++e) o[e] = (short)f2b(p[e] * inv);
        *(short8*)(arow + k0) = o;
    }
}

// ---- pv: split-k partial O chunks (fp32 into sc area), 3-buf pipeline -----------
__global__ __launch_bounds__(256) void k_pv(const ushort_t* __restrict__ attn,
                                            const ushort_t* __restrict__ vcT,
                                            float* __restrict__ opbase, int g0) {
    const int z = blockIdx.x, hh = g0 + z;
    int pp = blockIdx.y, byi = 15, c;
    for (;;) {
        int cb = (byi >> 2) + 1;
        if (pp < cb) { c = pp; break; }
        pp -= cb;
        --byi;
    }
    const int nt = min(4, byi + 1 - c * 4) * 4;
    const ushort_t* ap = attn + (size_t)z * NN + (size_t)(byi * 128) * 2048 + c * 512;
    const ushort_t* vp = vcT + (size_t)hh * 131072 + c * 512;
    float* op = opbase + (size_t)z * NN + (size_t)(c * 2048) * 64;
    __shared__ __align__(16) ushort_t lds[3][6144];
    const int l = threadIdx.x & 63, w = threadIdx.x >> 6, mb = w * 32;
    auto STAGE = [&](int t, ushort_t* buf) {
        if (t >= nt) return;
        const int k0 = t * 32;
        for (int u = w * 3; u < w * 3 + 3; ++u) {
            if (u < 8) stage16(ap + k0, 2048, buf, u);
            else stage16(vp + k0, 2048, buf + 4096, u - 8);
        }
    };
    STAGE(0, lds[0]);
    STAGE(1, lds[1]);
    f32x4 acc[2][4] = {};
    for (int t = 0; t < nt; ++t) {
        if (t + 1 < nt) wait_vm3(); else wait_vm0();
        __builtin_amdgcn_s_barrier();
        STAGE(t + 2, lds[(t + 2) % 3]);
        const ushort_t* buf = lds[t % 3];
        short8 fa[2], fb[4];
#pragma unroll
        for (int i = 0; i < 2; ++i) fa[i] = lfrag(buf, mb + i * 16, l);
#pragma unroll
        for (int j = 0; j < 4; ++j) fb[j] = lfrag(buf + 4096, j * 16, l);
#pragma unroll
        for (int i = 0; i < 2; ++i)
#pragma unroll
            for (int j = 0; j < 4; ++j) acc[i][j] = MFMA16(fa[i], fb[j], acc[i][j]);
    }
#pragma unroll
    for (int i = 0; i < 2; ++i)
#pragma unroll
        for (int j = 0; j < 4; ++j)
#pragma unroll
            for (int r = 0; r < 4; ++r) {
                int gi = byi * 128 + mb + i * 16 + (l >> 4) * 4 + r;
                int dd = j * 16 + (l & 15);
                op[(size_t)gi * 64 + dd] = acc[i][j][r];
            }
}

// ---- pv combine: sum chunks -> bf16 attno ---------------------------------------
__global__ __launch_bounds__(256) void k_pvc(const float* __restrict__ opall,
                                             ushort_t* __restrict__ attno, int g0) {
    const int z = blockIdx.x >> 9, rem = blockIdx.x & 511;
    const int i = rem * 4 + (threadIdx.x >> 6), d = threadIdx.x & 63;
    const int hh = g0 + z, b = hh >> 3, h = hh & 7;
    const float* op = opall + (size_t)z * NN;
    const int nc = (i >> 9) + 1;
    float a = 0.f;
    for (int c = 0; c < nc; ++c) a += op[(size_t)(c * 2048 + i) * 64 + d];
    attno[(size_t)(b * 2048 + i) * 512 + h * 64 + d] = f2b(a);
}

// ---- final = attno @ Wout^T (single bf16), 3-buf pipeline -----------------------
__global__ __launch_bounds__(256) void k_outproj(const ushort_t* __restrict__ attno,
                                                 const ushort_t* __restrict__ woh,
                                                 float* __restrict__ out) {
    __shared__ __align__(16) ushort_t lds[3][8192];
    const int m0 = blockIdx.y * 128, n0 = blockIdx.x * 128;
    const int l = threadIdx.x & 63, w = threadIdx.x >> 6;
    const int mb = (w >> 1) * 64, nb = (w & 1) * 64;
    const ushort_t* pa = attno + (size_t)m0 * DI;
    const ushort_t* pb = woh + (size_t)n0 * DI;
    auto STAGE = [&](int t, ushort_t* buf) {
        if (t >= 16) return;
        const int k0 = t * 32;
        for (int u = w * 4; u < w * 4 + 4; ++u) {
            if (u < 8) stage16(pa + k0, DI, buf, u);
            else stage16(pb + k0, DI, buf + 4096, u - 8);
        }
    };
    STAGE(0, lds[0]);
    STAGE(1, lds[1]);
    f32x4 acc[4][4] = {};
    for (int t = 0; t < 16; ++t) {
        if (t + 1 < 16) wait_vm4(); else wait_vm0();
        __builtin_amdgcn_s_barrier();
        STAGE(t + 2, lds[(t + 2) % 3]);
        const ushort_t* buf = lds[t % 3];
        short8 fa[4], fb[4];
#pragma unroll
        for (int i = 0; i < 4; ++i) fa[i] = lfrag(buf, mb + i * 16, l);
#pragma unroll
        for (int j = 0; j < 4; ++j) fb[j] = lfrag(buf + 4096, nb + j * 16, l);
#pragma unroll
        for (int i = 0; i < 4; ++i)
#pragma unroll
            for (int j = 0; j < 4; ++j) acc[i][j] = MFMA16(fa[i], fb[j], acc[i][j]);
    }
#pragma unroll
    for (int i = 0; i < 4; ++i)
#pragma unroll
        for (int j = 0; j < 4; ++j)
#pragma unroll
            for (int r = 0; r < 4; ++r) {
                int m = m0 + mb + i * 16 + (l >> 4) * 4 + r;
                int n = n0 + nb + j * 16 + (l & 15);
                out[(size_t)m * DM + n] = acc[i][j][r];
            }
}

extern "C" void kernel_launch(void* const* d_in, const int* in_sizes, int n_in,
                              void* d_out, int out_size, void* d_ws, size_t ws_size,
                              hipStream_t stream) {
    const float* x = (const float*)d_in[0];
    const float* Wqkv = (const float*)d_in[1];
    const float* Wout = (const float*)d_in[2];
    float* out = (float*)d_out;

    const size_t fixedb = 33554432ull;          // qh + vcT + attno (bytes)
    const size_t perh = 26214400ull;            // Ph (8MB) + diag (1MB) + sc f32 (16MB)
    int g = 0;
    for (int cand : {16, 8, 4, 2, 1})
        if (fixedb + perh * (size_t)cand <= ws_size) { g = cand; break; }
    if (!g) return;

    ushort_t* qh = (ushort_t*)d_ws;          // 12,582,912 el
    ushort_t* vcT = qh + 12582912;           // 2,097,152 el
    ushort_t* attno = vcT + 2097152;         // 2,097,152 el
    ushort_t* pool = attno + 2097152;
    // cvt/proj phase aliases (dead after k_proj):
    ushort_t* xh = pool;                     // 4,194,304
    ushort_t* wh = xh + 4194304;             // 3,145,728
    // group phase:
    ushort_t* Ph = pool;                                  // g*NN (attn after softmax)
    ushort_t* t1dh = Ph + (size_t)g * NN;                 // g*262144
    ushort_t* lkdh = t1dh + (size_t)g * 262144;           // g*262144
    float* scf = (float*)(lkdh + (size_t)g * 262144);     // g*NN f32 (pv partials too)
    // outproj phase:
    ushort_t* woh = pool;

    k_cvt<<<dim3(1024), 256, 0, stream>>>((const float4*)x, xh, nullptr, 1048576, 0);
    k_cvt<<<dim3(1024), 256, 0, stream>>>((const float4*)Wqkv, wh, nullptr, 786432, 0);
    k_proj<<<dim3(24, 32), 256, 0, stream>>>(xh, wh, qh, vcT);

    for (int g0 = 0; g0 < 16; g0 += g) {
        k_tl<<<dim3(2 * g, 136), 256, 0, stream>>>(qh, Ph, t1dh, lkdh, g0);
        k_scores<<<dim3(g, 136), 256, 0, stream>>>(Ph, t1dh, lkdh, qh, scf, g0);
        k_softmax<<<dim3(2048 * g), 256, 0, stream>>>(scf, Ph);
        k_pv<<<dim3(g, 40), 256, 0, stream>>>(Ph, vcT, scf, g0);
        k_pvc<<<dim3(512 * g), 256, 0, stream>>>(scf, attno, g0);
    }

    k_cvt<<<dim3(512), 256, 0, stream>>>((const float4*)Wout, woh, nullptr, 131072, 0);
    k_outproj<<<dim3(8, 32), 256, 0, stream>>>(attno, woh, out);
}